// Round 2
// baseline (156.057 us; speedup 1.0000x reference)
//
#include <hip/hip_runtime.h>
#include <hip/hip_bf16.h>

#define NN 8192
#define FF 256
#define NEGV -9000000000000000.0f

typedef __bf16 bf16x8 __attribute__((ext_vector_type(8)));
typedef float f32x4 __attribute__((ext_vector_type(4)));

__device__ __forceinline__ void load_lds16(const void* g, void* l) {
  auto gp = (const __attribute__((address_space(1))) void*)(uintptr_t)g;
  auto lp = (__attribute__((address_space(3))) void*)(uint32_t)(uintptr_t)l;
  __builtin_amdgcn_global_load_lds(gp, lp, 16, 0, 0);
}

// ---------------- kernel 1: convert inputs -> bf16 [8192,256]; W_ih/W_hh -> Wc bf16 [1536,256] ----
__global__ __launch_bounds__(256) void k_convert(const float* __restrict__ inputs,
                                                 const float* __restrict__ Wih,
                                                 const float* __restrict__ Whh,
                                                 __hip_bfloat16* __restrict__ ibf,
                                                 __hip_bfloat16* __restrict__ Wc) {
  const int gid = blockIdx.x * 256 + threadIdx.x;   // 311296 threads total
  const size_t NI = (size_t)NN * FF;                // 2,097,152
  const size_t base = (size_t)gid * 8;
  const float* src;
  __hip_bfloat16* dst;
  if (base < NI) { src = inputs + base; dst = ibf + base; }
  else {
    const size_t wo = base - NI;                    // 0 .. 393215
    dst = Wc + wo;
    src = (wo < 196608) ? (Wih + wo) : (Whh + (wo - 196608));
  }
  const float4 v0 = *(const float4*)src;
  const float4 v1 = *(const float4*)(src + 4);
  union { __hip_bfloat16 h[8]; uint4 u; } t;
  t.h[0] = __float2bfloat16(v0.x); t.h[1] = __float2bfloat16(v0.y);
  t.h[2] = __float2bfloat16(v0.z); t.h[3] = __float2bfloat16(v0.w);
  t.h[4] = __float2bfloat16(v1.x); t.h[5] = __float2bfloat16(v1.y);
  t.h[6] = __float2bfloat16(v1.z); t.h[7] = __float2bfloat16(v1.w);
  *(uint4*)dst = t.u;
}

// ---------------- kernel 2: fused gather + dual GEMM + GRU + dot-reduce -> s1, s2 -------------
// Block = 32 rows. Wave w covers features w*16.. within each 64-feature block fb.
// acc gate order: 0=ir 1=iz 2=in 3=hr 4=hz 5=hn. Only s1[32],s2[32] written per block.
__global__ __launch_bounds__(256) void k_gru(const __hip_bfloat16* __restrict__ ibf,
                                             const __hip_bfloat16* __restrict__ Wc,
                                             const float* __restrict__ inputs,
                                             const int* __restrict__ nbr,
                                             const float* __restrict__ b_ih,
                                             const float* __restrict__ b_hh,
                                             const float* __restrict__ a,
                                             float* __restrict__ s1,
                                             float* __restrict__ s2) {
  __shared__ __align__(16) __hip_bfloat16 Ax[32 * 256];   // 16 KB, xor-swizzled chunks
  __shared__ __align__(16) __hip_bfloat16 Ah[32 * 256];   // 16 KB
  __shared__ int hrow_s[32];
  __shared__ float r1[4][32], r2[4][32];
  const int rb = blockIdx.x * 32;
  const int tid = threadIdx.x;
  const int w = tid >> 6, l = tid & 63;
  const int fl = l & 15, q = l >> 4;

  if (tid < 32) hrow_s[tid] = nbr[2 * (rb + tid)];

  // Stage 32 gathered rows of x and h (bf16, 512 B each) into LDS.
  // LDS dest linear (wave-uniform base + lane*16); global source pre-swizzled:
  // LDS slot (r, c') holds global chunk (c' ^ (r&7)).
  {
    const int rlb = w * 8;
#pragma unroll
    for (int j = 0; j < 4; ++j) {
      const int r = rlb + j * 2 + (l >> 5);         // local row this lane stages
      const int cs = l & 31;                        // LDS chunk slot
      const int gc = cs ^ (r & 7);                  // global chunk
      const int xr = nbr[2 * (rb + r) + 1];
      const int hr_ = nbr[2 * (rb + r)];
      load_lds16((const char*)(ibf + (size_t)xr * FF) + gc * 16,
                 (char*)Ax + (rlb + j * 2) * 512);
      load_lds16((const char*)(ibf + (size_t)hr_ * FF) + gc * 16,
                 (char*)Ah + (rlb + j * 2) * 512);
    }
  }
  __syncthreads();

  float p1[8] = {0.f, 0.f, 0.f, 0.f, 0.f, 0.f, 0.f, 0.f};
  float p2[8] = {0.f, 0.f, 0.f, 0.f, 0.f, 0.f, 0.f, 0.f};

  for (int fb = 0; fb < 4; ++fb) {
    const int f = fb * 64 + w * 16 + fl;            // this lane's feature column
    const float bir = b_ih[f], biz = b_ih[256 + f], bin_ = b_ih[512 + f];
    const float bhr = b_hh[f], bhz = b_hh[256 + f], bhn = b_hh[512 + f];
    const float a1f = a[f], a2f = a[256 + f];

    f32x4 acc[6][2];
#pragma unroll
    for (int g = 0; g < 6; ++g) { acc[g][0] = (f32x4){0,0,0,0}; acc[g][1] = (f32x4){0,0,0,0}; }

    bf16x8 af[2][8];
    // A-frags from Ax (swizzled read): row = m*16+fl, chunk c = ks*4+q
#pragma unroll
    for (int m = 0; m < 2; ++m)
#pragma unroll
      for (int ks = 0; ks < 8; ++ks) {
        const int row = m * 16 + fl;
        const int c = ks * 4 + q;
        af[m][ks] = *(const bf16x8*)((const char*)Ax + row * 512 + (c ^ (row & 7)) * 16);
      }
#pragma unroll
    for (int g = 0; g < 3; ++g) {
      const __hip_bfloat16* bp = Wc + (size_t)(g * 256 + f) * FF + q * 8;
#pragma unroll
      for (int ks = 0; ks < 8; ++ks) {
        const bf16x8 bf = *(const bf16x8*)(bp + ks * 32);
        acc[g][0] = __builtin_amdgcn_mfma_f32_16x16x32_bf16(af[0][ks], bf, acc[g][0], 0, 0, 0);
        acc[g][1] = __builtin_amdgcn_mfma_f32_16x16x32_bf16(af[1][ks], bf, acc[g][1], 0, 0, 0);
      }
    }
    // A-frags from Ah (reuse registers)
#pragma unroll
    for (int m = 0; m < 2; ++m)
#pragma unroll
      for (int ks = 0; ks < 8; ++ks) {
        const int row = m * 16 + fl;
        const int c = ks * 4 + q;
        af[m][ks] = *(const bf16x8*)((const char*)Ah + row * 512 + (c ^ (row & 7)) * 16);
      }
#pragma unroll
    for (int g = 0; g < 3; ++g) {
      const __hip_bfloat16* bp = Wc + (size_t)(768 + g * 256 + f) * FF + q * 8;
#pragma unroll
      for (int ks = 0; ks < 8; ++ks) {
        const bf16x8 bf = *(const bf16x8*)(bp + ks * 32);
        acc[3 + g][0] = __builtin_amdgcn_mfma_f32_16x16x32_bf16(af[0][ks], bf, acc[3 + g][0], 0, 0, 0);
        acc[3 + g][1] = __builtin_amdgcn_mfma_f32_16x16x32_bf16(af[1][ks], bf, acc[3 + g][1], 0, 0, 0);
      }
    }

    // GRU epilogue for this lane's feature f, 8 rows (C/D: col=lane&15, row=q*4+j)
#pragma unroll
    for (int m = 0; m < 2; ++m)
#pragma unroll
      for (int j = 0; j < 4; ++j) {
        const int row = m * 16 + q * 4 + j;
        const float ir = acc[0][m][j] + bir;
        const float iz = acc[1][m][j] + biz;
        const float in_ = acc[2][m][j] + bin_;
        const float hrv = acc[3][m][j] + bhr;
        const float hzv = acc[4][m][j] + bhz;
        const float hnv = acc[5][m][j] + bhn;
        const float r_ = 1.f / (1.f + __expf(-(ir + hrv)));
        const float z_ = 1.f / (1.f + __expf(-(iz + hzv)));
        const float n_ = tanhf(in_ + r_ * hnv);
        const float hval = inputs[(size_t)hrow_s[row] * FF + f];
        const float o = (1.f - z_) * n_ + z_ * hval;
        p1[m * 4 + j] += o * a1f;
        p2[m * 4 + j] += o * a2f;
      }
  }

  // reduce over the 16 feature-lanes in each quarter-wave
#pragma unroll
  for (int i = 0; i < 8; ++i) {
#pragma unroll
    for (int off = 1; off < 16; off <<= 1) {
      p1[i] += __shfl_xor(p1[i], off);
      p2[i] += __shfl_xor(p2[i], off);
    }
  }
  if (fl == 0) {
#pragma unroll
    for (int m = 0; m < 2; ++m)
#pragma unroll
      for (int j = 0; j < 4; ++j) {
        const int row = m * 16 + q * 4 + j;
        r1[w][row] = p1[m * 4 + j];
        r2[w][row] = p2[m * 4 + j];
      }
  }
  __syncthreads();
  if (tid < 32) {
    s1[rb + tid] = r1[0][tid] + r1[1][tid] + r1[2][tid] + r1[3][tid];
  } else if (tid < 64) {
    const int t2 = tid - 32;
    s2[rb + t2] = r2[0][t2] + r2[1][t2] + r2[2][t2] + r2[3][t2];
  }
}

// ---------------- kernel 3: masked row softmax, e-values in registers ----------------
__global__ __launch_bounds__(256) void k_softmax(const int* __restrict__ adj,
                                                 const float* __restrict__ s1,
                                                 const float* __restrict__ s2,
                                                 float* __restrict__ out) {
  __shared__ __align__(16) float s2s[NN];
  __shared__ float red[8];
  const int row = blockIdx.x;
  const int t = threadIdx.x;
#pragma unroll
  for (int k = 0; k < 8; ++k) {
    const int v = k * 256 + t;
    *(float4*)(s2s + v * 4) = *(const float4*)(s2 + v * 4);
  }
  const float s1v = s1[row];
  __syncthreads();
  const int4* adjv = (const int4*)(adj + (size_t)row * NN);
  float e[32];
  float tmax = -3.4e38f;
#pragma unroll
  for (int k = 0; k < 8; ++k) {
    const int v = k * 256 + t;
    const int4 a4 = adjv[v];
    const float4 sv = *(const float4*)(s2s + v * 4);
    float x0 = s1v + sv.x; x0 = (x0 > 0.f) ? x0 : 0.2f * x0;
    float x1 = s1v + sv.y; x1 = (x1 > 0.f) ? x1 : 0.2f * x1;
    float x2 = s1v + sv.z; x2 = (x2 > 0.f) ? x2 : 0.2f * x2;
    float x3 = s1v + sv.w; x3 = (x3 > 0.f) ? x3 : 0.2f * x3;
    e[4 * k + 0] = (a4.x > 0) ? x0 : NEGV;
    e[4 * k + 1] = (a4.y > 0) ? x1 : NEGV;
    e[4 * k + 2] = (a4.z > 0) ? x2 : NEGV;
    e[4 * k + 3] = (a4.w > 0) ? x3 : NEGV;
    tmax = fmaxf(tmax, fmaxf(fmaxf(e[4 * k], e[4 * k + 1]), fmaxf(e[4 * k + 2], e[4 * k + 3])));
  }
#pragma unroll
  for (int off = 32; off; off >>= 1) tmax = fmaxf(tmax, __shfl_xor(tmax, off));
  if ((t & 63) == 0) red[t >> 6] = tmax;
  __syncthreads();
  const float rmax = fmaxf(fmaxf(red[0], red[1]), fmaxf(red[2], red[3]));
  float tsum = 0.f;
#pragma unroll
  for (int i = 0; i < 32; ++i) { e[i] = __expf(e[i] - rmax); tsum += e[i]; }
#pragma unroll
  for (int off = 32; off; off >>= 1) tsum += __shfl_xor(tsum, off);
  if ((t & 63) == 0) red[4 + (t >> 6)] = tsum;
  __syncthreads();
  const float inv = 1.f / (red[4] + red[5] + red[6] + red[7]);
  float* orow = out + (size_t)row * NN;
#pragma unroll
  for (int k = 0; k < 8; ++k) {
    const int v = k * 256 + t;
    float4 o;
    o.x = e[4 * k + 0] * inv;
    o.y = e[4 * k + 1] * inv;
    o.z = e[4 * k + 2] * inv;
    o.w = e[4 * k + 3] * inv;
    *(float4*)(orow + v * 4) = o;
  }
}

extern "C" void kernel_launch(void* const* d_in, const int* in_sizes, int n_in,
                              void* d_out, int out_size, void* d_ws, size_t ws_size,
                              hipStream_t stream) {
  const float* inputs = (const float*)d_in[0];
  const float* W_ih   = (const float*)d_in[1];
  const float* W_hh   = (const float*)d_in[2];
  const float* b_ih   = (const float*)d_in[3];
  const float* b_hh   = (const float*)d_in[4];
  const float* a      = (const float*)d_in[5];
  const int*   nbr    = (const int*)d_in[6];
  const int*   adj    = (const int*)d_in[7];
  float* out = (float*)d_out;

  // Scratch inside d_out (fully overwritten by k_softmax at the end):
  //   [64MB, 68MB): ibf bf16 [8192, 256]
  //   [80MB, ...) : Wc  bf16 [1536, 256]  (W_ih rows 0-767, W_hh rows 768-1535)
  __hip_bfloat16* ibf = (__hip_bfloat16*)((char*)d_out + (64u << 20));
  __hip_bfloat16* Wc  = (__hip_bfloat16*)((char*)d_out + (80u << 20));
  float* s1 = (float*)d_ws;        // 32 KB
  float* s2 = s1 + NN;             // 32 KB

  k_convert<<<1216, 256, 0, stream>>>(inputs, W_ih, W_hh, ibf, Wc);
  k_gru<<<256, 256, 0, stream>>>(ibf, Wc, inputs, nbr, b_ih, b_hh, a, s1, s2);
  k_softmax<<<NN, 256, 0, stream>>>(adj, s1, s2, out);
}

// Round 3
// 132.697 us; speedup vs baseline: 1.1760x; 1.1760x over previous
//
#include <hip/hip_runtime.h>
#include <hip/hip_bf16.h>

#define NN 8192
#define FF 256
#define NEGV -9000000000000000.0f

typedef __bf16 bf16x8 __attribute__((ext_vector_type(8)));
typedef float f32x4 __attribute__((ext_vector_type(4)));
typedef int i32x4 __attribute__((ext_vector_type(4)));

__device__ __forceinline__ void load_lds16(const void* g, void* l) {
  auto gp = (const __attribute__((address_space(1))) void*)(uintptr_t)g;
  auto lp = (__attribute__((address_space(3))) void*)(uint32_t)(uintptr_t)l;
  __builtin_amdgcn_global_load_lds(gp, lp, 16, 0, 0);
}

// ---------------- kernel 1: convert inputs -> bf16 [8192,256]; W_ih/W_hh -> Wc bf16 [1536,256] ----
__global__ __launch_bounds__(256) void k_convert(const float* __restrict__ inputs,
                                                 const float* __restrict__ Wih,
                                                 const float* __restrict__ Whh,
                                                 __hip_bfloat16* __restrict__ ibf,
                                                 __hip_bfloat16* __restrict__ Wc) {
  const int gid = blockIdx.x * 256 + threadIdx.x;   // 311296 threads total
  const size_t NI = (size_t)NN * FF;                // 2,097,152
  const size_t base = (size_t)gid * 8;
  const float* src;
  __hip_bfloat16* dst;
  if (base < NI) { src = inputs + base; dst = ibf + base; }
  else {
    const size_t wo = base - NI;                    // 0 .. 393215
    dst = Wc + wo;
    src = (wo < 196608) ? (Wih + wo) : (Whh + (wo - 196608));
  }
  const float4 v0 = *(const float4*)src;
  const float4 v1 = *(const float4*)(src + 4);
  union { __hip_bfloat16 h[8]; uint4 u; } t;
  t.h[0] = __float2bfloat16(v0.x); t.h[1] = __float2bfloat16(v0.y);
  t.h[2] = __float2bfloat16(v0.z); t.h[3] = __float2bfloat16(v0.w);
  t.h[4] = __float2bfloat16(v1.x); t.h[5] = __float2bfloat16(v1.y);
  t.h[6] = __float2bfloat16(v1.z); t.h[7] = __float2bfloat16(v1.w);
  *(uint4*)dst = t.u;
}

// ---------------- kernel 2: fused gather + dual GEMM + GRU + dot-reduce -> partial s1, s2 ------
// Block = 32 rows x 64 features (fb = blockIdx.y). Wave w covers features fb*64 + w*16 + lane&15.
// acc gate order: 0=ir 1=iz 2=in 3=hr 4=hz 5=hn. Writes p1[fb][32], p2[fb][32].
__global__ __launch_bounds__(256) void k_gru(const __hip_bfloat16* __restrict__ ibf,
                                             const __hip_bfloat16* __restrict__ Wc,
                                             const float* __restrict__ inputs,
                                             const int* __restrict__ nbr,
                                             const float* __restrict__ b_ih,
                                             const float* __restrict__ b_hh,
                                             const float* __restrict__ a,
                                             float* __restrict__ p1a,
                                             float* __restrict__ p2a) {
  __shared__ __align__(16) __hip_bfloat16 Ax[32 * 256];   // 16 KB, xor-swizzled chunks
  __shared__ __align__(16) __hip_bfloat16 Ah[32 * 256];   // 16 KB
  __shared__ int hrow_s[32];
  __shared__ float r1[4][32], r2[4][32];
  const int rb = blockIdx.x * 32;
  const int fb = blockIdx.y;
  const int tid = threadIdx.x;
  const int w = tid >> 6, l = tid & 63;
  const int fl = l & 15, q = l >> 4;

  if (tid < 32) hrow_s[tid] = nbr[2 * (rb + tid)];

  // Stage 32 gathered rows of x and h (bf16, 512 B each) into LDS.
  // LDS dest linear (wave-uniform base + lane*16); global source pre-swizzled:
  // LDS slot (r, c') holds global chunk (c' ^ (r&7)).
  {
    const int rlb = w * 8;
#pragma unroll
    for (int j = 0; j < 4; ++j) {
      const int r = rlb + j * 2 + (l >> 5);         // local row this lane stages
      const int cs = l & 31;                        // LDS chunk slot
      const int gc = cs ^ (r & 7);                  // global chunk
      const int xr = nbr[2 * (rb + r) + 1];
      const int hr_ = nbr[2 * (rb + r)];
      load_lds16((const char*)(ibf + (size_t)xr * FF) + gc * 16,
                 (char*)Ax + (rlb + j * 2) * 512);
      load_lds16((const char*)(ibf + (size_t)hr_ * FF) + gc * 16,
                 (char*)Ah + (rlb + j * 2) * 512);
    }
  }
  __syncthreads();

  float p1[8] = {0.f, 0.f, 0.f, 0.f, 0.f, 0.f, 0.f, 0.f};
  float p2[8] = {0.f, 0.f, 0.f, 0.f, 0.f, 0.f, 0.f, 0.f};

  const int f = fb * 64 + w * 16 + fl;              // this lane's feature column
  const float bir = b_ih[f], biz = b_ih[256 + f], bin_ = b_ih[512 + f];
  const float bhr = b_hh[f], bhz = b_hh[256 + f], bhn = b_hh[512 + f];
  const float a1f = a[f], a2f = a[256 + f];

  f32x4 acc[6][2];
#pragma unroll
  for (int g = 0; g < 6; ++g) { acc[g][0] = (f32x4){0,0,0,0}; acc[g][1] = (f32x4){0,0,0,0}; }

  bf16x8 af[2][8];
  // A-frags from Ax (swizzled read): row = m*16+fl, chunk c = ks*4+q
#pragma unroll
  for (int m = 0; m < 2; ++m)
#pragma unroll
    for (int ks = 0; ks < 8; ++ks) {
      const int row = m * 16 + fl;
      const int c = ks * 4 + q;
      af[m][ks] = *(const bf16x8*)((const char*)Ax + row * 512 + (c ^ (row & 7)) * 16);
    }
#pragma unroll
  for (int g = 0; g < 3; ++g) {
    const __hip_bfloat16* bp = Wc + (size_t)(g * 256 + f) * FF + q * 8;
#pragma unroll
    for (int ks = 0; ks < 8; ++ks) {
      const bf16x8 bf = *(const bf16x8*)(bp + ks * 32);
      acc[g][0] = __builtin_amdgcn_mfma_f32_16x16x32_bf16(af[0][ks], bf, acc[g][0], 0, 0, 0);
      acc[g][1] = __builtin_amdgcn_mfma_f32_16x16x32_bf16(af[1][ks], bf, acc[g][1], 0, 0, 0);
    }
  }
  // A-frags from Ah (reuse registers)
#pragma unroll
  for (int m = 0; m < 2; ++m)
#pragma unroll
    for (int ks = 0; ks < 8; ++ks) {
      const int row = m * 16 + fl;
      const int c = ks * 4 + q;
      af[m][ks] = *(const bf16x8*)((const char*)Ah + row * 512 + (c ^ (row & 7)) * 16);
    }
#pragma unroll
  for (int g = 0; g < 3; ++g) {
    const __hip_bfloat16* bp = Wc + (size_t)(768 + g * 256 + f) * FF + q * 8;
#pragma unroll
    for (int ks = 0; ks < 8; ++ks) {
      const bf16x8 bf = *(const bf16x8*)(bp + ks * 32);
      acc[3 + g][0] = __builtin_amdgcn_mfma_f32_16x16x32_bf16(af[0][ks], bf, acc[3 + g][0], 0, 0, 0);
      acc[3 + g][1] = __builtin_amdgcn_mfma_f32_16x16x32_bf16(af[1][ks], bf, acc[3 + g][1], 0, 0, 0);
    }
  }

  // GRU epilogue for this lane's feature f, 8 rows (C/D: col=lane&15, row=q*4+j)
#pragma unroll
  for (int m = 0; m < 2; ++m)
#pragma unroll
    for (int j = 0; j < 4; ++j) {
      const int row = m * 16 + q * 4 + j;
      const float ir = acc[0][m][j] + bir;
      const float iz = acc[1][m][j] + biz;
      const float in_ = acc[2][m][j] + bin_;
      const float hrv = acc[3][m][j] + bhr;
      const float hzv = acc[4][m][j] + bhz;
      const float hnv = acc[5][m][j] + bhn;
      const float r_ = 1.f / (1.f + __expf(-(ir + hrv)));
      const float z_ = 1.f / (1.f + __expf(-(iz + hzv)));
      const float n_ = tanhf(in_ + r_ * hnv);
      const float hval = inputs[(size_t)hrow_s[row] * FF + f];
      const float o = (1.f - z_) * n_ + z_ * hval;
      p1[m * 4 + j] += o * a1f;
      p2[m * 4 + j] += o * a2f;
    }

  // reduce over the 16 feature-lanes in each quarter-wave
#pragma unroll
  for (int i = 0; i < 8; ++i) {
#pragma unroll
    for (int off = 1; off < 16; off <<= 1) {
      p1[i] += __shfl_xor(p1[i], off);
      p2[i] += __shfl_xor(p2[i], off);
    }
  }
  if (fl == 0) {
#pragma unroll
    for (int m = 0; m < 2; ++m)
#pragma unroll
      for (int j = 0; j < 4; ++j) {
        const int row = m * 16 + q * 4 + j;
        r1[w][row] = p1[m * 4 + j];
        r2[w][row] = p2[m * 4 + j];
      }
  }
  __syncthreads();
  if (tid < 32) {
    p1a[fb * NN + rb + tid] = r1[0][tid] + r1[1][tid] + r1[2][tid] + r1[3][tid];
  } else if (tid < 64) {
    const int t2 = tid - 32;
    p2a[fb * NN + rb + t2] = r2[0][t2] + r2[1][t2] + r2[2][t2] + r2[3][t2];
  }
}

// ---------------- kernel 3: sum the 4 feature-block partials -> s1, s2 ----------------
__global__ __launch_bounds__(256) void k_reduce(const float* __restrict__ p1a,
                                                const float* __restrict__ p2a,
                                                float* __restrict__ s1,
                                                float* __restrict__ s2) {
  const int i = blockIdx.x * 256 + threadIdx.x;   // 8192 threads
  s1[i] = p1a[i] + p1a[NN + i] + p1a[2 * NN + i] + p1a[3 * NN + i];
  s2[i] = p2a[i] + p2a[NN + i] + p2a[2 * NN + i] + p2a[3 * NN + i];
}

// ---------------- kernel 4: masked row softmax, no-max (exp-safe), regs only ----------------
__global__ __launch_bounds__(256) void k_softmax(const int* __restrict__ adj,
                                                 const float* __restrict__ s1,
                                                 const float* __restrict__ s2,
                                                 float* __restrict__ out) {
  __shared__ float red[4];
  const int row = blockIdx.x;
  const int t = threadIdx.x;
  const i32x4* adjv = (const i32x4*)(adj + (size_t)row * NN);
  i32x4 a4[8];
#pragma unroll
  for (int k = 0; k < 8; ++k) a4[k] = __builtin_nontemporal_load(adjv + k * 256 + t);
  f32x4 sv[8];
#pragma unroll
  for (int k = 0; k < 8; ++k) sv[k] = *(const f32x4*)(s2 + (k * 256 + t) * 4);
  const float s1v = s1[row];

  float e[32];
  float tsum = 0.f;
#pragma unroll
  for (int k = 0; k < 8; ++k) {
#pragma unroll
    for (int c = 0; c < 4; ++c) {
      float x = s1v + sv[k][c];
      x = (x > 0.f) ? x : 0.2f * x;
      x = (a4[k][c] > 0) ? x : NEGV;
      x = __expf(x);                 // exp(NEGV) == 0 handles the mask exactly
      e[4 * k + c] = x;
      tsum += x;
    }
  }
#pragma unroll
  for (int off = 32; off; off >>= 1) tsum += __shfl_xor(tsum, off);
  if ((t & 63) == 0) red[t >> 6] = tsum;
  __syncthreads();
  const float inv = 1.f / (red[0] + red[1] + red[2] + red[3]);
  float* orow = out + (size_t)row * NN;
#pragma unroll
  for (int k = 0; k < 8; ++k) {
    const int v = k * 256 + t;
    f32x4 o;
#pragma unroll
    for (int c = 0; c < 4; ++c) o[c] = e[4 * k + c] * inv;
    __builtin_nontemporal_store(o, (f32x4*)(orow + v * 4));
  }
}

extern "C" void kernel_launch(void* const* d_in, const int* in_sizes, int n_in,
                              void* d_out, int out_size, void* d_ws, size_t ws_size,
                              hipStream_t stream) {
  const float* inputs = (const float*)d_in[0];
  const float* W_ih   = (const float*)d_in[1];
  const float* W_hh   = (const float*)d_in[2];
  const float* b_ih   = (const float*)d_in[3];
  const float* b_hh   = (const float*)d_in[4];
  const float* a      = (const float*)d_in[5];
  const int*   nbr    = (const int*)d_in[6];
  const int*   adj    = (const int*)d_in[7];
  float* out = (float*)d_out;

  // Scratch inside d_out (fully overwritten by k_softmax at the end):
  //   [64MB, 68MB): ibf bf16 [8192, 256]
  //   [80MB, ..) : Wc  bf16 [1536, 256]  (W_ih rows 0-767, W_hh rows 768-1535)
  //   [96MB, ..) : p1a f32 [4][8192]; p2a right after (128 KB each)
  __hip_bfloat16* ibf = (__hip_bfloat16*)((char*)d_out + (64u << 20));
  __hip_bfloat16* Wc  = (__hip_bfloat16*)((char*)d_out + (80u << 20));
  float* p1a = (float*)((char*)d_out + (96u << 20));
  float* p2a = p1a + 4 * NN;
  float* s1 = (float*)d_ws;        // 32 KB
  float* s2 = s1 + NN;             // 32 KB

  k_convert<<<1216, 256, 0, stream>>>(inputs, W_ih, W_hh, ibf, Wc);
  k_gru<<<dim3(256, 4), 256, 0, stream>>>(ibf, Wc, inputs, nbr, b_ih, b_hh, a, p1a, p2a);
  k_reduce<<<32, 256, 0, stream>>>(p1a, p2a, s1, s2);
  k_softmax<<<NN, 256, 0, stream>>>(adj, s1, s2, out);
}